// Round 1
// baseline (5741.481 us; speedup 1.0000x reference)
//
#include <hip/hip_runtime.h>

constexpr int Bn = 4;
constexpr int Nn = 160;
constexpr int SEGN = Bn * Nn * Nn;        // 102400 segments
constexpr unsigned NEG_FLIP = 0x007FFFFFu; // flip(-inf)

__device__ __forceinline__ unsigned flipf(float f) {
  unsigned u = __float_as_uint(f);
  return (u & 0x80000000u) ? ~u : (u | 0x80000000u);
}
__device__ __forceinline__ float unflipf(unsigned s) {
  return __uint_as_float((s & 0x80000000u) ? (s ^ 0x80000000u) : ~s);
}

// ---------------- init segment buffer to flip(-inf) ----------------
__global__ void k_init(uint4* __restrict__ seg, int n4) {
  int i = blockIdx.x * blockDim.x + threadIdx.x;
  int stride = gridDim.x * blockDim.x;
  uint4 v = make_uint4(NEG_FLIP, NEG_FLIP, NEG_FLIP, NEG_FLIP);
  for (; i < n4; i += stride) seg[i] = v;
}

// ---------------- fused edge MLP + scatter-max ----------------
// 32 edges/block, 256 threads. thread tile: 4 rows x 16 cols,
// col(j,jj) = j*128 + tx*4 + jj  (conflict-free b128 weight reads)
__global__ __launch_bounds__(256) void k_edge(
    const int* __restrict__ rel_type, const float* __restrict__ rel_error,
    const int* __restrict__ edge_pos, const int* __restrict__ rel_row,
    const float* __restrict__ type_tab, const float* __restrict__ pos_tab,
    const float* __restrict__ w1, const float* __restrict__ b1,
    const float* __restrict__ w2, const float* __restrict__ b2,
    const float* __restrict__ w3, const float* __restrict__ b3,
    unsigned* __restrict__ seg, int E) {
  __shared__ float e_lds[32][132];    // 16.9 KB (padded)
  __shared__ float h1_lds[32][256];   // 32 KB
  __shared__ float h2_lds[32][512];   // 64 KB
  __shared__ float wbuf[8192];        // 32 KB weight chunk

  const int tid = threadIdx.x;
  const int e0 = blockIdx.x * 32;
  const int ty = tid >> 5;   // 0..7 -> rows ty*4..ty*4+3
  const int tx = tid & 31;   // 0..31

  // ---- build e tile: concat(type_emb, rel_error) + pos_emb ----
  {
    int r = tid >> 3;
    int c0 = (tid & 7) * 16;
    int re = min(e0 + r, E - 1);
    int rt = rel_type[re];
    int ep = edge_pos[re];
#pragma unroll
    for (int j = 0; j < 16; ++j) {
      int c = c0 + j;
      float v = (c < 120) ? (rt ? type_tab[rt * 120 + c] : 0.f)
                          : rel_error[re * 8 + (c - 120)];
      e_lds[r][c] = v + pos_tab[ep * 128 + c];
    }
  }

  float acc[4][16];

  // ---- layer 1: [32x128] @ [128x256], relu ----
#pragma unroll
  for (int j = 0; j < 2; ++j)
#pragma unroll
    for (int jj = 0; jj < 4; ++jj) {
      float b = b1[j * 128 + tx * 4 + jj];
#pragma unroll
      for (int i = 0; i < 4; ++i) acc[i][j * 4 + jj] = b;
    }
  for (int k0 = 0; k0 < 128; k0 += 32) {
    __syncthreads();
    const float4* src = (const float4*)(w1 + k0 * 256);
    float4* dst = (float4*)wbuf;
#pragma unroll
    for (int i = 0; i < 8; ++i) dst[tid + i * 256] = src[tid + i * 256];
    __syncthreads();
#pragma unroll
    for (int kk = 0; kk < 32; ++kk) {
      float a[4];
#pragma unroll
      for (int i = 0; i < 4; ++i) a[i] = e_lds[ty * 4 + i][k0 + kk];
#pragma unroll
      for (int j = 0; j < 2; ++j) {
        const float4 w4 = *(const float4*)&wbuf[kk * 256 + j * 128 + tx * 4];
#pragma unroll
        for (int i = 0; i < 4; ++i) {
          acc[i][j * 4 + 0] = fmaf(a[i], w4.x, acc[i][j * 4 + 0]);
          acc[i][j * 4 + 1] = fmaf(a[i], w4.y, acc[i][j * 4 + 1]);
          acc[i][j * 4 + 2] = fmaf(a[i], w4.z, acc[i][j * 4 + 2]);
          acc[i][j * 4 + 3] = fmaf(a[i], w4.w, acc[i][j * 4 + 3]);
        }
      }
    }
  }
#pragma unroll
  for (int i = 0; i < 4; ++i)
#pragma unroll
    for (int j = 0; j < 2; ++j) {
      float4 v;
      v.x = fmaxf(acc[i][j * 4 + 0], 0.f);
      v.y = fmaxf(acc[i][j * 4 + 1], 0.f);
      v.z = fmaxf(acc[i][j * 4 + 2], 0.f);
      v.w = fmaxf(acc[i][j * 4 + 3], 0.f);
      *(float4*)&h1_lds[ty * 4 + i][j * 128 + tx * 4] = v;
    }

  // ---- layer 2: [32x256] @ [256x512], relu ----
#pragma unroll
  for (int j = 0; j < 4; ++j)
#pragma unroll
    for (int jj = 0; jj < 4; ++jj) {
      float b = b2[j * 128 + tx * 4 + jj];
#pragma unroll
      for (int i = 0; i < 4; ++i) acc[i][j * 4 + jj] = b;
    }
  for (int k0 = 0; k0 < 256; k0 += 16) {
    __syncthreads();
    const float4* src = (const float4*)(w2 + k0 * 512);
    float4* dst = (float4*)wbuf;
#pragma unroll
    for (int i = 0; i < 8; ++i) dst[tid + i * 256] = src[tid + i * 256];
    __syncthreads();
#pragma unroll
    for (int kk = 0; kk < 16; ++kk) {
      float a[4];
#pragma unroll
      for (int i = 0; i < 4; ++i) a[i] = h1_lds[ty * 4 + i][k0 + kk];
#pragma unroll
      for (int j = 0; j < 4; ++j) {
        const float4 w4 = *(const float4*)&wbuf[kk * 512 + j * 128 + tx * 4];
#pragma unroll
        for (int i = 0; i < 4; ++i) {
          acc[i][j * 4 + 0] = fmaf(a[i], w4.x, acc[i][j * 4 + 0]);
          acc[i][j * 4 + 1] = fmaf(a[i], w4.y, acc[i][j * 4 + 1]);
          acc[i][j * 4 + 2] = fmaf(a[i], w4.z, acc[i][j * 4 + 2]);
          acc[i][j * 4 + 3] = fmaf(a[i], w4.w, acc[i][j * 4 + 3]);
        }
      }
    }
  }
  __syncthreads();
#pragma unroll
  for (int i = 0; i < 4; ++i)
#pragma unroll
    for (int j = 0; j < 4; ++j) {
      float4 v;
      v.x = fmaxf(acc[i][j * 4 + 0], 0.f);
      v.y = fmaxf(acc[i][j * 4 + 1], 0.f);
      v.z = fmaxf(acc[i][j * 4 + 2], 0.f);
      v.w = fmaxf(acc[i][j * 4 + 3], 0.f);
      *(float4*)&h2_lds[ty * 4 + i][j * 128 + tx * 4] = v;
    }

  // ---- layer 3: [32x512] @ [512x512] (no relu) ----
#pragma unroll
  for (int j = 0; j < 4; ++j)
#pragma unroll
    for (int jj = 0; jj < 4; ++jj) {
      float b = b3[j * 128 + tx * 4 + jj];
#pragma unroll
      for (int i = 0; i < 4; ++i) acc[i][j * 4 + jj] = b;
    }
  for (int k0 = 0; k0 < 512; k0 += 16) {
    __syncthreads();
    const float4* src = (const float4*)(w3 + k0 * 512);
    float4* dst = (float4*)wbuf;
#pragma unroll
    for (int i = 0; i < 8; ++i) dst[tid + i * 256] = src[tid + i * 256];
    __syncthreads();
#pragma unroll
    for (int kk = 0; kk < 16; ++kk) {
      float a[4];
#pragma unroll
      for (int i = 0; i < 4; ++i) a[i] = h2_lds[ty * 4 + i][k0 + kk];
#pragma unroll
      for (int j = 0; j < 4; ++j) {
        const float4 w4 = *(const float4*)&wbuf[kk * 512 + j * 128 + tx * 4];
#pragma unroll
        for (int i = 0; i < 4; ++i) {
          acc[i][j * 4 + 0] = fmaf(a[i], w4.x, acc[i][j * 4 + 0]);
          acc[i][j * 4 + 1] = fmaf(a[i], w4.y, acc[i][j * 4 + 1]);
          acc[i][j * 4 + 2] = fmaf(a[i], w4.z, acc[i][j * 4 + 2]);
          acc[i][j * 4 + 3] = fmaf(a[i], w4.w, acc[i][j * 4 + 3]);
        }
      }
    }
  }

  // ---- scatter-max into seg (rel_row sorted -> merge runs within thread) ----
  int rows[4];
#pragma unroll
  for (int i = 0; i < 4; ++i) rows[i] = rel_row[min(e0 + ty * 4 + i, E - 1)];

  float m[16];
#pragma unroll
  for (int q = 0; q < 16; ++q) m[q] = acc[0][q];
  int cur = rows[0];
#pragma unroll
  for (int i = 1; i < 4; ++i) {
    if (rows[i] == cur) {
#pragma unroll
      for (int q = 0; q < 16; ++q) m[q] = fmaxf(m[q], acc[i][q]);
    } else {
      unsigned* dst = seg + (size_t)cur * 512;
#pragma unroll
      for (int j = 0; j < 4; ++j)
#pragma unroll
        for (int jj = 0; jj < 4; ++jj)
          atomicMax(dst + j * 128 + tx * 4 + jj, flipf(m[j * 4 + jj]));
      cur = rows[i];
#pragma unroll
      for (int q = 0; q < 16; ++q) m[q] = acc[i][q];
    }
  }
  {
    unsigned* dst = seg + (size_t)cur * 512;
#pragma unroll
    for (int j = 0; j < 4; ++j)
#pragma unroll
      for (int jj = 0; jj < 4; ++jj)
        atomicMax(dst + j * 128 + tx * 4 + jj, flipf(m[j * 4 + jj]));
  }
}

// ---------------- FC stage: relu -> LN -> GEMM [32x512]@[512x512] ----------------
// FIRST: input is flipped-u32 seg buffer + dist embedding; else plain float.
// In-place safe: block reads rows r0..r0+31 fully before writing the same rows.
template <bool FIRST>
__global__ __launch_bounds__(256) void k_fc512(
    const float* __restrict__ xin, const unsigned* __restrict__ segin,
    const int* __restrict__ dist, const float* __restrict__ dist_tab,
    const float* __restrict__ g, const float* __restrict__ be,
    const float* __restrict__ wf, const float* __restrict__ bf,
    float* __restrict__ xout) {
  __shared__ float a_lds[32][516];   // padded
  __shared__ float wbuf[8192];
  __shared__ float stat[32][2];
  const int tid = threadIdx.x;
  const int r0 = blockIdx.x * 32;
  const int ty = tid >> 5, tx = tid & 31;

  // prologue: load + (unflip + dist emb) + relu + LN stats
  {
    int r = tid >> 3, cp = tid & 7;
    int gr = r0 + r;
    float s1 = 0.f, s2 = 0.f;
    if constexpr (FIRST) {
      int di = dist[gr];
      const float* dt = dist_tab + (size_t)di * 512;
      for (int c = cp * 64; c < cp * 64 + 64; ++c) {
        unsigned sv = segin[(size_t)gr * 512 + c];
        float v = (sv == NEG_FLIP) ? 0.f : unflipf(sv);
        if (di) v += dt[c];
        v = fmaxf(v, 0.f);
        a_lds[r][c] = v; s1 += v; s2 += v * v;
      }
    } else {
      for (int c = cp * 64; c < cp * 64 + 64; ++c) {
        float v = fmaxf(xin[(size_t)gr * 512 + c], 0.f);
        a_lds[r][c] = v; s1 += v; s2 += v * v;
      }
    }
#pragma unroll
    for (int o = 4; o > 0; o >>= 1) { s1 += __shfl_down(s1, o); s2 += __shfl_down(s2, o); }
    if (cp == 0) {
      float mean = s1 * (1.f / 512.f);
      float var = s2 * (1.f / 512.f) - mean * mean;
      stat[r][0] = mean;
      stat[r][1] = rsqrtf(var + 1e-5f);
    }
    __syncthreads();
    float mean = stat[r][0], rs = stat[r][1];
    for (int c = cp * 64; c < cp * 64 + 64; ++c)
      a_lds[r][c] = (a_lds[r][c] - mean) * rs * g[c] + be[c];
  }

  // GEMM
  float acc[4][16];
#pragma unroll
  for (int j = 0; j < 4; ++j)
#pragma unroll
    for (int jj = 0; jj < 4; ++jj) {
      float b = bf[j * 128 + tx * 4 + jj];
#pragma unroll
      for (int i = 0; i < 4; ++i) acc[i][j * 4 + jj] = b;
    }
  for (int k0 = 0; k0 < 512; k0 += 16) {
    __syncthreads();
    const float4* src = (const float4*)(wf + (size_t)k0 * 512);
    float4* dst = (float4*)wbuf;
#pragma unroll
    for (int i = 0; i < 8; ++i) dst[tid + i * 256] = src[tid + i * 256];
    __syncthreads();
#pragma unroll
    for (int kk = 0; kk < 16; ++kk) {
      float a[4];
#pragma unroll
      for (int i = 0; i < 4; ++i) a[i] = a_lds[ty * 4 + i][k0 + kk];
#pragma unroll
      for (int j = 0; j < 4; ++j) {
        const float4 w4 = *(const float4*)&wbuf[kk * 512 + j * 128 + tx * 4];
#pragma unroll
        for (int i = 0; i < 4; ++i) {
          acc[i][j * 4 + 0] = fmaf(a[i], w4.x, acc[i][j * 4 + 0]);
          acc[i][j * 4 + 1] = fmaf(a[i], w4.y, acc[i][j * 4 + 1]);
          acc[i][j * 4 + 2] = fmaf(a[i], w4.z, acc[i][j * 4 + 2]);
          acc[i][j * 4 + 3] = fmaf(a[i], w4.w, acc[i][j * 4 + 3]);
        }
      }
    }
  }
#pragma unroll
  for (int i = 0; i < 4; ++i)
#pragma unroll
    for (int j = 0; j < 4; ++j) {
      float4 v = make_float4(acc[i][j * 4 + 0], acc[i][j * 4 + 1],
                             acc[i][j * 4 + 2], acc[i][j * 4 + 3]);
      *(float4*)&xout[(size_t)(r0 + ty * 4 + i) * 512 + j * 128 + tx * 4] = v;
    }
}

// ---------------- FC3: relu -> LN -> [32x512]@[512x16] ----------------
__global__ __launch_bounds__(256) void k_fc3(
    const float* __restrict__ xin,
    const float* __restrict__ g, const float* __restrict__ be,
    const float* __restrict__ wf, const float* __restrict__ bf,
    float* __restrict__ x3) {
  __shared__ float a_lds[32][516];
  __shared__ float wbuf[8192];   // full wf3 (512x16)
  __shared__ float stat[32][2];
  const int tid = threadIdx.x;
  const int r0 = blockIdx.x * 32;

  {
    const float4* src = (const float4*)wf;
    float4* dst = (float4*)wbuf;
#pragma unroll
    for (int i = 0; i < 8; ++i) dst[tid + i * 256] = src[tid + i * 256];
  }

  int r = tid >> 3, cp = tid & 7;
  int gr = r0 + r;
  float s1 = 0.f, s2 = 0.f;
  for (int c = cp * 64; c < cp * 64 + 64; ++c) {
    float v = fmaxf(xin[(size_t)gr * 512 + c], 0.f);
    a_lds[r][c] = v; s1 += v; s2 += v * v;
  }
#pragma unroll
  for (int o = 4; o > 0; o >>= 1) { s1 += __shfl_down(s1, o); s2 += __shfl_down(s2, o); }
  if (cp == 0) {
    float mean = s1 * (1.f / 512.f);
    float var = s2 * (1.f / 512.f) - mean * mean;
    stat[r][0] = mean;
    stat[r][1] = rsqrtf(var + 1e-5f);
  }
  __syncthreads();
  {
    float mean = stat[r][0], rs = stat[r][1];
    for (int c = cp * 64; c < cp * 64 + 64; ++c)
      a_lds[r][c] = (a_lds[r][c] - mean) * rs * g[c] + be[c];
  }
  __syncthreads();

#pragma unroll
  for (int e = 0; e < 2; ++e) {
    int o = tid + e * 256;
    int row = o >> 4, col = o & 15;
    float acc = bf[col];
#pragma unroll 4
    for (int k = 0; k < 512; ++k)
      acc = fmaf(a_lds[row][k], wbuf[k * 16 + col], acc);
    x3[(size_t)(r0 + row) * 16 + col] = acc;
  }
}

// ---------------- triu mask + symmetrize ----------------
__global__ void k_sym(const float* __restrict__ x3, float* __restrict__ out) {
  int t = blockIdx.x * 256 + threadIdx.x;   // one float4 per thread
  if (t >= SEGN * 4) return;
  int q = t & 3;
  int cell = t >> 2;
  int j = cell % Nn;
  int tmp = cell / Nn;
  int i = tmp % Nn;
  int b = tmp / Nn;
  float4 v = make_float4(0.f, 0.f, 0.f, 0.f);
  if (i <= j) v = *(const float4*)&x3[(size_t)cell * 16 + q * 4];
  if (j <= i) {
    int cell2 = (b * Nn + j) * Nn + i;
    float4 u = *(const float4*)&x3[(size_t)cell2 * 16 + q * 4];
    v.x += u.x; v.y += u.y; v.z += u.z; v.w += u.w;
  }
  *(float4*)&out[(size_t)t * 4] = v;
}

extern "C" void kernel_launch(void* const* d_in, const int* in_sizes, int n_in,
                              void* d_out, int out_size, void* d_ws, size_t ws_size,
                              hipStream_t stream) {
  const int*   rel_type  = (const int*)d_in[0];
  const float* rel_error = (const float*)d_in[1];
  const int*   edge_pos  = (const int*)d_in[2];
  const int*   dist      = (const int*)d_in[3];
  const int*   rel_row   = (const int*)d_in[4];
  // d_in[5] rel_col (unused), d_in[6] batch_num, d_in[7] max_node (hardcoded 4/160)
  const float* type_tab = (const float*)d_in[8];
  const float* pos_tab  = (const float*)d_in[9];
  const float* dist_tab = (const float*)d_in[10];
  const float* w1 = (const float*)d_in[11]; const float* b1 = (const float*)d_in[12];
  const float* w2 = (const float*)d_in[13]; const float* b2 = (const float*)d_in[14];
  const float* w3 = (const float*)d_in[15]; const float* b3 = (const float*)d_in[16];
  const float* g1 = (const float*)d_in[17]; const float* be1 = (const float*)d_in[18];
  const float* wf1 = (const float*)d_in[19]; const float* bf1 = (const float*)d_in[20];
  const float* g2 = (const float*)d_in[21]; const float* be2 = (const float*)d_in[22];
  const float* wf2 = (const float*)d_in[23]; const float* bf2 = (const float*)d_in[24];
  const float* g3 = (const float*)d_in[25]; const float* be3 = (const float*)d_in[26];
  const float* wf3 = (const float*)d_in[27]; const float* bf3 = (const float*)d_in[28];

  const int E = in_sizes[0];
  const size_t seg_bytes = (size_t)SEGN * 512 * 4;
  const size_t x3_bytes  = (size_t)SEGN * 16 * 4;
  if (ws_size < seg_bytes + x3_bytes) return;  // insufficient workspace

  unsigned* seg = (unsigned*)d_ws;
  float*    x3  = (float*)((char*)d_ws + seg_bytes);
  float*    out = (float*)d_out;

  k_init<<<2048, 256, 0, stream>>>((uint4*)seg, SEGN * 512 / 4);
  k_edge<<<(E + 31) / 32, 256, 0, stream>>>(rel_type, rel_error, edge_pos, rel_row,
                                            type_tab, pos_tab, w1, b1, w2, b2, w3, b3,
                                            seg, E);
  k_fc512<true><<<SEGN / 32, 256, 0, stream>>>(nullptr, seg, dist, dist_tab,
                                               g1, be1, wf1, bf1, (float*)seg);
  k_fc512<false><<<SEGN / 32, 256, 0, stream>>>((const float*)seg, nullptr, nullptr, nullptr,
                                                g2, be2, wf2, bf2, (float*)seg);
  k_fc3<<<SEGN / 32, 256, 0, stream>>>((const float*)seg, g3, be3, wf3, bf3, x3);
  k_sym<<<(SEGN * 4 + 255) / 256, 256, 0, stream>>>(x3, out);
}

// Round 2
// 1283.916 us; speedup vs baseline: 4.4718x; 4.4718x over previous
//
#include <hip/hip_runtime.h>

typedef __attribute__((ext_vector_type(8))) _Float16 half8;
typedef __attribute__((ext_vector_type(4))) _Float16 half4;
typedef __attribute__((ext_vector_type(4))) float f32x4;

constexpr int Bn = 4;
constexpr int Nn = 160;
constexpr int SEGN = Bn * Nn * Nn;        // 102400 segments
constexpr unsigned NEG_FLIP = 0x007FFFFFu; // flip(-inf)

__device__ __forceinline__ unsigned flipf(float f) {
  unsigned u = __float_as_uint(f);
  return (u & 0x80000000u) ? ~u : (u | 0x80000000u);
}
__device__ __forceinline__ float unflipf(unsigned s) {
  return __uint_as_float((s & 0x80000000u) ? (s ^ 0x80000000u) : ~s);
}

__device__ __forceinline__ void gload_lds16(const void* g, void* l) {
  __builtin_amdgcn_global_load_lds(
      (const __attribute__((address_space(1))) unsigned int*)g,
      (__attribute__((address_space(3))) unsigned int*)l, 16, 0, 0);
}

// ---------------- init segment buffer to flip(-inf) ----------------
__global__ void k_init(uint4* __restrict__ seg, int n4) {
  int i = blockIdx.x * blockDim.x + threadIdx.x;
  int stride = gridDim.x * blockDim.x;
  uint4 v = make_uint4(NEG_FLIP, NEG_FLIP, NEG_FLIP, NEG_FLIP);
  for (; i < n4; i += stride) seg[i] = v;
}

// ---------------- weight prepass: f32 [K][N] -> f16 [N][K] ----------------
__global__ void k_prep(const float* __restrict__ w1, const float* __restrict__ w2,
                       const float* __restrict__ w3, const float* __restrict__ wf1,
                       const float* __restrict__ wf2, _Float16* __restrict__ o1,
                       _Float16* __restrict__ o2, _Float16* __restrict__ o3,
                       _Float16* __restrict__ of1, _Float16* __restrict__ of2) {
  int t = blockIdx.x * 256 + threadIdx.x;
  const float* src; _Float16* dst; int K, N, local;
  if (t < 32768)       { src = w1;  dst = o1;  K = 128; N = 256; local = t; }
  else if (t < 163840) { src = w2;  dst = o2;  K = 256; N = 512; local = t - 32768; }
  else if (t < 425984) { src = w3;  dst = o3;  K = 512; N = 512; local = t - 163840; }
  else if (t < 688128) { src = wf1; dst = of1; K = 512; N = 512; local = t - 425984; }
  else if (t < 950272) { src = wf2; dst = of2; K = 512; N = 512; local = t - 688128; }
  else return;
  int k = local & (K - 1);
  int n = local / K;
  dst[local] = (_Float16)src[(size_t)k * N + n];
}

// ---------------- shared MFMA layer machinery ----------------
// A in LDS: f16 [rows][K], row stride K*2 bytes, byte ^= ((row&7)<<4) swizzle.
// B staged per 32-K chunk into wbuf: rows [n][32], slot s' holds k-seg s'^(n&3).
// Wave tiling: 8 waves, wave w owns all 4 M-tiles x NT N-tiles (w*NT..w*NT+NT-1).
template <int K, int NT>
__device__ __forceinline__ void do_layer(const _Float16* __restrict__ wt,
                                         const char* a_base, char* wbuf,
                                         f32x4 (&acc)[4][NT], int tid) {
  const int w = tid >> 6, lane = tid & 63, ln15 = lane & 15, kg = lane >> 4;
  for (int c = 0; c < K / 32; ++c) {
    __syncthreads();
#pragma unroll
    for (int t = 0; t < NT; ++t) {
      int d16 = (t * 8 + w) * 64 + lane;
      int n = d16 >> 2, sp = d16 & 3;
      const char* src = (const char*)wt + n * (K * 2) + c * 64 + ((sp ^ (n & 3)) << 4);
      gload_lds16(src, wbuf + ((t * 8 + w) << 10));
    }
    __syncthreads();
    half8 a[4], b[NT];
#pragma unroll
    for (int mt = 0; mt < 4; ++mt) {
      int row = mt * 16 + ln15;
      int byte = (row * (K * 2) + c * 64 + kg * 16) ^ ((row & 7) << 4);
      a[mt] = *(const half8*)(a_base + byte);
    }
#pragma unroll
    for (int nt = 0; nt < NT; ++nt) {
      int n = (w * NT + nt) * 16 + ln15;
      b[nt] = *(const half8*)(wbuf + n * 64 + ((kg ^ (n & 3)) << 4));
    }
#pragma unroll
    for (int mt = 0; mt < 4; ++mt)
#pragma unroll
      for (int nt = 0; nt < NT; ++nt)
        acc[mt][nt] = __builtin_amdgcn_mfma_f32_16x16x32_f16(a[mt], b[nt], acc[mt][nt], 0, 0, 0);
  }
}

template <int NT>
__device__ __forceinline__ void init_acc(const float* __restrict__ bias,
                                         f32x4 (&acc)[4][NT], int tid) {
  const int w = tid >> 6, ln15 = tid & 15;
#pragma unroll
  for (int nt = 0; nt < NT; ++nt) {
    float bv = bias[(w * NT + nt) * 16 + ln15];
    f32x4 s = {bv, bv, bv, bv};
#pragma unroll
    for (int mt = 0; mt < 4; ++mt) acc[mt][nt] = s;
  }
}

// C layout: col = lane&15 (within N-tile), row = (lane>>4)*4 + j  [m89 verified]
template <int NT, bool RELU>
__device__ __forceinline__ void store_h(char* h, int rowB, const f32x4 (&acc)[4][NT], int tid) {
  const int w = tid >> 6, lane = tid & 63, ln15 = lane & 15, kg = lane >> 4;
#pragma unroll
  for (int mt = 0; mt < 4; ++mt)
#pragma unroll
    for (int nt = 0; nt < NT; ++nt)
#pragma unroll
      for (int j = 0; j < 4; ++j) {
        int row = mt * 16 + kg * 4 + j;
        int n = (w * NT + nt) * 16 + ln15;
        float v = acc[mt][nt][j];
        if (RELU) v = fmaxf(v, 0.f);
        *(_Float16*)(h + ((row * rowB + n * 2) ^ ((row & 7) << 4))) = (_Float16)v;
      }
}

// ---------------- fused edge MLP (MFMA) + scatter-max ----------------
// 64 edges/block, 512 threads (8 waves).
__global__ __launch_bounds__(512) void k_edge(
    const int* __restrict__ rel_type, const float* __restrict__ rel_error,
    const int* __restrict__ edge_pos, const int* __restrict__ rel_row,
    const float* __restrict__ type_tab, const float* __restrict__ pos_tab,
    const _Float16* __restrict__ w1t, const float* __restrict__ b1,
    const _Float16* __restrict__ w2t, const float* __restrict__ b2,
    const _Float16* __restrict__ w3t, const float* __restrict__ b3,
    unsigned* __restrict__ seg, int E) {
  __shared__ __align__(16) char smem[131072];
  __shared__ int rr[64];
  char* h1 = smem;            // [64][256] f16, rowB 512, swizzled
  char* h2 = smem + 32768;    // [64][512] f16, rowB 1024, swizzled
  char* e  = smem + 32768;    // [64][128] f16, rowB 256 (dead before h2 written)
  char* wbuf = smem + 98304;  // 32 KB chunk buffer

  const int tid = threadIdx.x;
  const int e0 = blockIdx.x * 64;

  // ---- build e tile ----
  {
    int r = tid >> 3, c0 = (tid & 7) * 16;
    int re = min(e0 + r, E - 1);
    int rt = rel_type[re];
    int ep = edge_pos[re];
#pragma unroll
    for (int s = 0; s < 2; ++s) {
      half8 hv;
#pragma unroll
      for (int q = 0; q < 8; ++q) {
        int cc = c0 + s * 8 + q;
        float v = (cc < 120) ? (rt ? type_tab[rt * 120 + cc] : 0.f)
                             : rel_error[(size_t)re * 8 + (cc - 120)];
        v += pos_tab[ep * 128 + cc];
        hv[q] = (_Float16)v;
      }
      int byte = (r * 256 + (c0 + s * 8) * 2) ^ ((r & 7) << 4);
      *(half8*)(e + byte) = hv;
    }
    if (tid < 64) rr[tid] = rel_row[min(e0 + tid, E - 1)];
  }

  {  // layer 1: [64x128]@[128x256] + relu -> h1
    f32x4 acc[4][2];
    init_acc<2>(b1, acc, tid);
    do_layer<128, 2>(w1t, e, wbuf, acc, tid);
    store_h<2, true>(h1, 512, acc, tid);
  }
  {  // layer 2: [64x256]@[256x512] + relu -> h2
    f32x4 acc[4][4];
    init_acc<4>(b2, acc, tid);
    do_layer<256, 4>(w2t, h1, wbuf, acc, tid);
    store_h<4, true>(h2, 1024, acc, tid);
  }
  {  // layer 3: [64x512]@[512x512] -> scatter-max
    f32x4 acc[4][4];
    init_acc<4>(b3, acc, tid);
    do_layer<512, 4>(w3t, h2, wbuf, acc, tid);

    const int w = tid >> 6, lane = tid & 63, ln15 = lane & 15, kg = lane >> 4;
#pragma unroll
    for (int mt = 0; mt < 4; ++mt) {
      int rbase = mt * 16 + kg * 4;
      float m[4];
      int cur = rr[rbase];
#pragma unroll
      for (int nt = 0; nt < 4; ++nt) m[nt] = acc[mt][nt][0];
#pragma unroll
      for (int j = 1; j < 4; ++j) {
        int rj = rr[rbase + j];
        if (rj == cur) {
#pragma unroll
          for (int nt = 0; nt < 4; ++nt) m[nt] = fmaxf(m[nt], acc[mt][nt][j]);
        } else {
          unsigned* dst = seg + (size_t)cur * 512;
#pragma unroll
          for (int nt = 0; nt < 4; ++nt)
            atomicMax(dst + (w * 4 + nt) * 16 + ln15, flipf(m[nt]));
          cur = rj;
#pragma unroll
          for (int nt = 0; nt < 4; ++nt) m[nt] = acc[mt][nt][j];
        }
      }
      unsigned* dst = seg + (size_t)cur * 512;
#pragma unroll
      for (int nt = 0; nt < 4; ++nt)
        atomicMax(dst + (w * 4 + nt) * 16 + ln15, flipf(m[nt]));
    }
  }
}

// ---------------- FC stage (MFMA): relu -> LN -> [64x512]@[512x512] ----------------
template <bool FIRST>
__global__ __launch_bounds__(512) void k_fc512(
    const float* __restrict__ xin, const unsigned* __restrict__ segin,
    const int* __restrict__ dist, const float* __restrict__ dist_tab,
    const float* __restrict__ g, const float* __restrict__ be,
    const _Float16* __restrict__ wft, const float* __restrict__ bf,
    float* __restrict__ xout) {
  __shared__ __align__(16) char smem[98304];
  __shared__ float stat[64][2];
  char* a = smem;             // [64][512] f16, rowB 1024, swizzled
  char* wbuf = smem + 65536;  // 32 KB

  const int tid = threadIdx.x;
  const int r0 = blockIdx.x * 64;
  const int r = tid >> 3, cp = tid & 7;
  const int gr = r0 + r;

  // pass 1: load + relu (+unflip/dist), store f16, accumulate stats in f32
  {
    float s1 = 0.f, s2 = 0.f;
    int di = 0;
    const float* dt = nullptr;
    if constexpr (FIRST) { di = dist[gr]; dt = dist_tab + (size_t)di * 512; }
#pragma unroll
    for (int i = 0; i < 16; ++i) {
      int c = cp * 64 + i * 4;
      float v0, v1, v2, v3;
      if constexpr (FIRST) {
        uint4 sv = *(const uint4*)(segin + (size_t)gr * 512 + c);
        v0 = (sv.x == NEG_FLIP) ? 0.f : unflipf(sv.x);
        v1 = (sv.y == NEG_FLIP) ? 0.f : unflipf(sv.y);
        v2 = (sv.z == NEG_FLIP) ? 0.f : unflipf(sv.z);
        v3 = (sv.w == NEG_FLIP) ? 0.f : unflipf(sv.w);
        if (di) { v0 += dt[c]; v1 += dt[c + 1]; v2 += dt[c + 2]; v3 += dt[c + 3]; }
      } else {
        float4 xv = *(const float4*)(xin + (size_t)gr * 512 + c);
        v0 = xv.x; v1 = xv.y; v2 = xv.z; v3 = xv.w;
      }
      v0 = fmaxf(v0, 0.f); v1 = fmaxf(v1, 0.f); v2 = fmaxf(v2, 0.f); v3 = fmaxf(v3, 0.f);
      s1 += v0 + v1 + v2 + v3;
      s2 += v0 * v0 + v1 * v1 + v2 * v2 + v3 * v3;
      half4 hv = {(_Float16)v0, (_Float16)v1, (_Float16)v2, (_Float16)v3};
      *(half4*)(a + ((r * 1024 + c * 2) ^ ((r & 7) << 4))) = hv;
    }
#pragma unroll
    for (int o = 4; o > 0; o >>= 1) { s1 += __shfl_down(s1, o); s2 += __shfl_down(s2, o); }
    if (cp == 0) {
      float mean = s1 * (1.f / 512.f);
      float var = s2 * (1.f / 512.f) - mean * mean;
      stat[r][0] = mean;
      stat[r][1] = rsqrtf(var + 1e-5f);
    }
  }
  __syncthreads();
  // pass 2: normalize in LDS
  {
    float mean = stat[r][0], rs = stat[r][1];
#pragma unroll
    for (int i = 0; i < 16; ++i) {
      int c = cp * 64 + i * 4;
      int byte = (r * 1024 + c * 2) ^ ((r & 7) << 4);
      half4 hv = *(half4*)(a + byte);
      float4 g4 = *(const float4*)(g + c);
      float4 b4 = *(const float4*)(be + c);
      half4 ov = {(_Float16)(((float)hv[0] - mean) * rs * g4.x + b4.x),
                  (_Float16)(((float)hv[1] - mean) * rs * g4.y + b4.y),
                  (_Float16)(((float)hv[2] - mean) * rs * g4.z + b4.z),
                  (_Float16)(((float)hv[3] - mean) * rs * g4.w + b4.w)};
      *(half4*)(a + byte) = ov;
    }
  }

  f32x4 acc[4][4];
  init_acc<4>(bf, acc, tid);
  do_layer<512, 4>(wft, a, wbuf, acc, tid);

  const int w = tid >> 6, lane = tid & 63, ln15 = lane & 15, kg = lane >> 4;
#pragma unroll
  for (int mt = 0; mt < 4; ++mt)
#pragma unroll
    for (int nt = 0; nt < 4; ++nt)
#pragma unroll
      for (int j = 0; j < 4; ++j) {
        int row = mt * 16 + kg * 4 + j;
        int n = (w * 4 + nt) * 16 + ln15;
        xout[(size_t)(r0 + row) * 512 + n] = acc[mt][nt][j];
      }
}

// ---------------- FC3: relu -> LN -> [32x512]@[512x16] ----------------
__global__ __launch_bounds__(256) void k_fc3(
    const float* __restrict__ xin,
    const float* __restrict__ g, const float* __restrict__ be,
    const float* __restrict__ wf, const float* __restrict__ bf,
    float* __restrict__ x3) {
  __shared__ float a_lds[32][516];
  __shared__ float wbuf[8192];
  __shared__ float stat[32][2];
  const int tid = threadIdx.x;
  const int r0 = blockIdx.x * 32;

  {
    const float4* src = (const float4*)wf;
    float4* dst = (float4*)wbuf;
#pragma unroll
    for (int i = 0; i < 8; ++i) dst[tid + i * 256] = src[tid + i * 256];
  }

  int r = tid >> 3, cp = tid & 7;
  int gr = r0 + r;
  float s1 = 0.f, s2 = 0.f;
  for (int c = cp * 64; c < cp * 64 + 64; ++c) {
    float v = fmaxf(xin[(size_t)gr * 512 + c], 0.f);
    a_lds[r][c] = v; s1 += v; s2 += v * v;
  }
#pragma unroll
  for (int o = 4; o > 0; o >>= 1) { s1 += __shfl_down(s1, o); s2 += __shfl_down(s2, o); }
  if (cp == 0) {
    float mean = s1 * (1.f / 512.f);
    float var = s2 * (1.f / 512.f) - mean * mean;
    stat[r][0] = mean;
    stat[r][1] = rsqrtf(var + 1e-5f);
  }
  __syncthreads();
  {
    float mean = stat[r][0], rs = stat[r][1];
    for (int c = cp * 64; c < cp * 64 + 64; ++c)
      a_lds[r][c] = (a_lds[r][c] - mean) * rs * g[c] + be[c];
  }
  __syncthreads();

#pragma unroll
  for (int e = 0; e < 2; ++e) {
    int o = tid + e * 256;
    int row = o >> 4, col = o & 15;
    float acc = bf[col];
#pragma unroll 4
    for (int k = 0; k < 512; ++k)
      acc = fmaf(a_lds[row][k], wbuf[k * 16 + col], acc);
    x3[(size_t)(r0 + row) * 16 + col] = acc;
  }
}

// ---------------- triu mask + symmetrize ----------------
__global__ void k_sym(const float* __restrict__ x3, float* __restrict__ out) {
  int t = blockIdx.x * 256 + threadIdx.x;
  if (t >= SEGN * 4) return;
  int q = t & 3;
  int cell = t >> 2;
  int j = cell % Nn;
  int tmp = cell / Nn;
  int i = tmp % Nn;
  int b = tmp / Nn;
  float4 v = make_float4(0.f, 0.f, 0.f, 0.f);
  if (i <= j) v = *(const float4*)&x3[(size_t)cell * 16 + q * 4];
  if (j <= i) {
    int cell2 = (b * Nn + j) * Nn + i;
    float4 u = *(const float4*)&x3[(size_t)cell2 * 16 + q * 4];
    v.x += u.x; v.y += u.y; v.z += u.z; v.w += u.w;
  }
  *(float4*)&out[(size_t)t * 4] = v;
}

extern "C" void kernel_launch(void* const* d_in, const int* in_sizes, int n_in,
                              void* d_out, int out_size, void* d_ws, size_t ws_size,
                              hipStream_t stream) {
  const int*   rel_type  = (const int*)d_in[0];
  const float* rel_error = (const float*)d_in[1];
  const int*   edge_pos  = (const int*)d_in[2];
  const int*   dist      = (const int*)d_in[3];
  const int*   rel_row   = (const int*)d_in[4];
  const float* type_tab = (const float*)d_in[8];
  const float* pos_tab  = (const float*)d_in[9];
  const float* dist_tab = (const float*)d_in[10];
  const float* w1 = (const float*)d_in[11]; const float* b1 = (const float*)d_in[12];
  const float* w2 = (const float*)d_in[13]; const float* b2 = (const float*)d_in[14];
  const float* w3 = (const float*)d_in[15]; const float* b3 = (const float*)d_in[16];
  const float* g1 = (const float*)d_in[17]; const float* be1 = (const float*)d_in[18];
  const float* wf1 = (const float*)d_in[19]; const float* bf1 = (const float*)d_in[20];
  const float* g2 = (const float*)d_in[21]; const float* be2 = (const float*)d_in[22];
  const float* wf2 = (const float*)d_in[23]; const float* bf2 = (const float*)d_in[24];
  const float* g3 = (const float*)d_in[25]; const float* be3 = (const float*)d_in[26];
  const float* wf3 = (const float*)d_in[27]; const float* bf3 = (const float*)d_in[28];

  const int E = in_sizes[0];
  const size_t seg_bytes = (size_t)SEGN * 512 * 4;     // 209.7 MB
  const size_t x3_bytes  = (size_t)SEGN * 16 * 4;      // 6.55 MB
  const size_t wt_bytes  = (32768 + 131072 + 262144 * 3) * sizeof(_Float16);
  if (ws_size < seg_bytes + x3_bytes + wt_bytes) return;

  unsigned*  seg = (unsigned*)d_ws;
  float*     x3  = (float*)((char*)d_ws + seg_bytes);
  _Float16*  w1t = (_Float16*)((char*)d_ws + seg_bytes + x3_bytes);
  _Float16*  w2t = w1t + 32768;
  _Float16*  w3t = w2t + 131072;
  _Float16*  wf1t = w3t + 262144;
  _Float16*  wf2t = wf1t + 262144;
  float*     out = (float*)d_out;

  k_prep<<<3712, 256, 0, stream>>>(w1, w2, w3, wf1, wf2, w1t, w2t, w3t, wf1t, wf2t);
  k_init<<<2048, 256, 0, stream>>>((uint4*)seg, SEGN * 512 / 4);
  k_edge<<<(E + 63) / 64, 512, 0, stream>>>(rel_type, rel_error, edge_pos, rel_row,
                                            type_tab, pos_tab, w1t, b1, w2t, b2, w3t, b3,
                                            seg, E);
  k_fc512<true><<<SEGN / 64, 512, 0, stream>>>(nullptr, seg, dist, dist_tab,
                                               g1, be1, wf1t, bf1, (float*)seg);
  k_fc512<false><<<SEGN / 64, 512, 0, stream>>>((const float*)seg, nullptr, nullptr, nullptr,
                                                g2, be2, wf2t, bf2, (float*)seg);
  k_fc3<<<SEGN / 32, 256, 0, stream>>>((const float*)seg, g3, be3, wf3, bf3, x3);
  k_sym<<<(SEGN * 4 + 255) / 256, 256, 0, stream>>>(x3, out);
}

// Round 4
// 899.158 us; speedup vs baseline: 6.3854x; 1.4279x over previous
//
#include <hip/hip_runtime.h>

typedef __attribute__((ext_vector_type(8))) _Float16 half8;
typedef __attribute__((ext_vector_type(4))) _Float16 half4;
typedef __attribute__((ext_vector_type(4))) float f32x4;

constexpr int Bn = 4;
constexpr int Nn = 160;
constexpr int SEGN = Bn * Nn * Nn;        // 102400 segments
constexpr unsigned NEG_FLIP = 0x007FFFFFu; // flip(-inf)

__device__ __forceinline__ unsigned flipf(float f) {
  unsigned u = __float_as_uint(f);
  return (u & 0x80000000u) ? ~u : (u | 0x80000000u);
}
__device__ __forceinline__ float unflipf(unsigned s) {
  return __uint_as_float((s & 0x80000000u) ? (s ^ 0x80000000u) : ~s);
}

// ---------------- init segment buffer to flip(-inf) ----------------
__global__ void k_init(uint4* __restrict__ seg, int n4) {
  int i = blockIdx.x * blockDim.x + threadIdx.x;
  int stride = gridDim.x * blockDim.x;
  uint4 v = make_uint4(NEG_FLIP, NEG_FLIP, NEG_FLIP, NEG_FLIP);
  for (; i < n4; i += stride) seg[i] = v;
}

// ------- weight prepass: f32 [K][N] -> f16 chunk-blocked [k/32][N][32] -------
// (wf3: [512][16] -> [16][512] plain transpose)
__global__ void k_prep(const float* __restrict__ w1, const float* __restrict__ w2,
                       const float* __restrict__ w3, const float* __restrict__ wf1,
                       const float* __restrict__ wf2, const float* __restrict__ wf3,
                       _Float16* __restrict__ o1, _Float16* __restrict__ o2,
                       _Float16* __restrict__ o3, _Float16* __restrict__ of1,
                       _Float16* __restrict__ of2, _Float16* __restrict__ of3) {
  int t = blockIdx.x * 256 + threadIdx.x;
  const float* src; _Float16* dst; int N, local; bool is3 = false;
  if (t < 32768)       { src = w1;  dst = o1;  N = 256; local = t; }
  else if (t < 163840) { src = w2;  dst = o2;  N = 512; local = t - 32768; }
  else if (t < 425984) { src = w3;  dst = o3;  N = 512; local = t - 163840; }
  else if (t < 688128) { src = wf1; dst = of1; N = 512; local = t - 425984; }
  else if (t < 950272) { src = wf2; dst = of2; N = 512; local = t - 688128; }
  else if (t < 958464) { src = wf3; dst = of3; N = 16;  local = t - 950272; is3 = true; }
  else return;
  int k = local / N;
  int n = local - k * N;
  if (is3) dst[n * 512 + k] = (_Float16)src[local];
  else dst[(size_t)((k >> 5) * N + n) * 32 + (k & 31)] = (_Float16)src[local];
}

// ---------------- barrier-free MFMA layer, B direct from global (L2) ----------------
// A in LDS: f16 [rows][K], rowB = 2K bytes, byte ^= ((row&7)<<4).
// W chunk-blocked global [c][N][32] f16: a wave's (n-tile, kg) half8 is a
// coalesced 16B slice of a contiguous 1KB region.
template <int K, int NT>
__device__ __forceinline__ void do_layer_g(const _Float16* __restrict__ wt,
                                           const char* a_base,
                                           f32x4 (&acc)[4][NT], int tid) {
  constexpr int C = K / 32;
  constexpr int N = NT * 128;
  constexpr int rowB = K * 2;
  const int w = tid >> 6, lane = tid & 63, ln15 = lane & 15, kg = lane >> 4;
  const char* wb = (const char*)wt;
#pragma unroll
  for (int c = 0; c < C; ++c) {
    half8 a[4], b[NT];
#pragma unroll
    for (int nt = 0; nt < NT; ++nt) {
      int n = (w * NT + nt) * 16 + ln15;
      b[nt] = *(const half8*)(wb + (size_t)c * (N * 64) + n * 64 + kg * 16);
    }
#pragma unroll
    for (int mt = 0; mt < 4; ++mt) {
      int row = mt * 16 + ln15;
      int byte = (row * rowB + c * 64 + kg * 16) ^ ((row & 7) << 4);
      a[mt] = *(const half8*)(a_base + byte);
    }
#pragma unroll
    for (int mt = 0; mt < 4; ++mt)
#pragma unroll
      for (int nt = 0; nt < NT; ++nt)
        acc[mt][nt] = __builtin_amdgcn_mfma_f32_16x16x32_f16(a[mt], b[nt], acc[mt][nt], 0, 0, 0);
  }
}

template <int NT>
__device__ __forceinline__ void init_acc(const float* __restrict__ bias,
                                         f32x4 (&acc)[4][NT], int tid) {
  const int w = tid >> 6, ln15 = tid & 15;
#pragma unroll
  for (int nt = 0; nt < NT; ++nt) {
    float bv = bias[(w * NT + nt) * 16 + ln15];
    f32x4 s = {bv, bv, bv, bv};
#pragma unroll
    for (int mt = 0; mt < 4; ++mt) acc[mt][nt] = s;
  }
}

// C layout: col = lane&15, row = (lane>>4)*4 + j  [m89 verified]
template <int NT, bool RELU>
__device__ __forceinline__ void store_h(char* h, int rowB, const f32x4 (&acc)[4][NT], int tid) {
  const int w = tid >> 6, lane = tid & 63, ln15 = lane & 15, kg = lane >> 4;
#pragma unroll
  for (int mt = 0; mt < 4; ++mt)
#pragma unroll
    for (int nt = 0; nt < NT; ++nt)
#pragma unroll
      for (int j = 0; j < 4; ++j) {
        int row = mt * 16 + kg * 4 + j;
        int n = (w * NT + nt) * 16 + ln15;
        float v = acc[mt][nt][j];
        if (RELU) v = fmaxf(v, 0.f);
        *(_Float16*)(h + ((row * rowB + n * 2) ^ ((row & 7) << 4))) = (_Float16)v;
      }
}

// ---------------- fused edge MLP (MFMA) + scatter-max ----------------
__global__ __launch_bounds__(512) void k_edge(
    const int* __restrict__ rel_type, const float* __restrict__ rel_error,
    const int* __restrict__ edge_pos, const int* __restrict__ rel_row,
    const float* __restrict__ type_tab, const float* __restrict__ pos_tab,
    const _Float16* __restrict__ w1t, const float* __restrict__ b1,
    const _Float16* __restrict__ w2t, const float* __restrict__ b2,
    const _Float16* __restrict__ w3t, const float* __restrict__ b3,
    unsigned* __restrict__ seg, int E) {
  __shared__ __align__(16) char smem[98304];
  __shared__ int rr[64];
  char* h1 = smem;            // [64][256] f16, rowB 512
  char* h2 = smem + 32768;    // [64][512] f16, rowB 1024
  char* e  = smem + 32768;    // [64][128] f16, rowB 256 (dead before h2 written)

  const int tid = threadIdx.x;
  const int e0 = blockIdx.x * 64;

  // ---- build e tile ----
  {
    int r = tid >> 3, c0 = (tid & 7) * 16;
    int re = min(e0 + r, E - 1);
    int rt = rel_type[re];
    int ep = edge_pos[re];
#pragma unroll
    for (int s = 0; s < 2; ++s) {
      half8 hv;
#pragma unroll
      for (int q = 0; q < 8; ++q) {
        int cc = c0 + s * 8 + q;
        float v = (cc < 120) ? (rt ? type_tab[rt * 120 + cc] : 0.f)
                             : rel_error[(size_t)re * 8 + (cc - 120)];
        v += pos_tab[ep * 128 + cc];
        hv[q] = (_Float16)v;
      }
      int byte = (r * 256 + (c0 + s * 8) * 2) ^ ((r & 7) << 4);
      *(half8*)(e + byte) = hv;
    }
    if (tid < 64) rr[tid] = rel_row[min(e0 + tid, E - 1)];
  }
  __syncthreads();

  {  // layer 1: [64x128]@[128x256] + relu -> h1
    f32x4 acc[4][2];
    init_acc<2>(b1, acc, tid);
    do_layer_g<128, 2>(w1t, e, acc, tid);
    store_h<2, true>(h1, 512, acc, tid);
  }
  __syncthreads();
  {  // layer 2: [64x256]@[256x512] + relu -> h2 (overwrites e, safe: e reads drained)
    f32x4 acc[4][4];
    init_acc<4>(b2, acc, tid);
    do_layer_g<256, 4>(w2t, h1, acc, tid);
    store_h<4, true>(h2, 1024, acc, tid);
  }
  __syncthreads();
  {  // layer 3: [64x512]@[512x512] -> scatter-max
    f32x4 acc[4][4];
    init_acc<4>(b3, acc, tid);
    do_layer_g<512, 4>(w3t, h2, acc, tid);

    const int w = tid >> 6, lane = tid & 63, ln15 = lane & 15, kg = lane >> 4;
#pragma unroll
    for (int mt = 0; mt < 4; ++mt) {
      int rbase = mt * 16 + kg * 4;
      float m[4];
      int cur = rr[rbase];
#pragma unroll
      for (int nt = 0; nt < 4; ++nt) m[nt] = acc[mt][nt][0];
#pragma unroll
      for (int j = 1; j < 4; ++j) {
        int rj = rr[rbase + j];
        if (rj == cur) {
#pragma unroll
          for (int nt = 0; nt < 4; ++nt) m[nt] = fmaxf(m[nt], acc[mt][nt][j]);
        } else {
          unsigned* dst = seg + (size_t)cur * 512;
#pragma unroll
          for (int nt = 0; nt < 4; ++nt)
            atomicMax(dst + (w * 4 + nt) * 16 + ln15, flipf(m[nt]));
          cur = rj;
#pragma unroll
          for (int nt = 0; nt < 4; ++nt) m[nt] = acc[mt][nt][j];
        }
      }
      unsigned* dst = seg + (size_t)cur * 512;
#pragma unroll
      for (int nt = 0; nt < 4; ++nt)
        atomicMax(dst + (w * 4 + nt) * 16 + ln15, flipf(m[nt]));
    }
  }
}

// ---- in-register epilogue: relu -> LN (shfl + 2-stage LDS) -> store f16 ----
// In-place safe: dst writes happen after barrier #2; all GEMM reads of dst
// were issued before barrier #1.
__device__ __forceinline__ void epi_ln_store(f32x4 (&acc)[4][4], char* dst,
                                             float* st1, float* st2,
                                             float* stM, float* stR,
                                             const float* __restrict__ g,
                                             const float* __restrict__ be, int tid) {
  const int w = tid >> 6, lane = tid & 63, ln15 = lane & 15, kg = lane >> 4;
#pragma unroll
  for (int mt = 0; mt < 4; ++mt)
#pragma unroll
    for (int nt = 0; nt < 4; ++nt)
#pragma unroll
      for (int j = 0; j < 4; ++j) acc[mt][nt][j] = fmaxf(acc[mt][nt][j], 0.f);
#pragma unroll
  for (int mt = 0; mt < 4; ++mt)
#pragma unroll
    for (int j = 0; j < 4; ++j) {
      float a = 0.f, b = 0.f;
#pragma unroll
      for (int nt = 0; nt < 4; ++nt) { float v = acc[mt][nt][j]; a += v; b += v * v; }
#pragma unroll
      for (int m = 1; m < 16; m <<= 1) { a += __shfl_xor(a, m); b += __shfl_xor(b, m); }
      if (ln15 == 0) {
        int r = mt * 16 + kg * 4 + j;
        st1[w * 64 + r] = a;
        st2[w * 64 + r] = b;
      }
    }
  __syncthreads();
  if (tid < 64) {
    float a = 0.f, b = 0.f;
#pragma unroll
    for (int ww = 0; ww < 8; ++ww) { a += st1[ww * 64 + tid]; b += st2[ww * 64 + tid]; }
    float mean = a * (1.f / 512.f);
    float var = b * (1.f / 512.f) - mean * mean;
    stM[tid] = mean;
    stR[tid] = rsqrtf(var + 1e-5f);
  }
  __syncthreads();
  float gv[4], bv[4];
#pragma unroll
  for (int nt = 0; nt < 4; ++nt) {
    int n = (w * 4 + nt) * 16 + ln15;
    gv[nt] = g[n]; bv[nt] = be[n];
  }
#pragma unroll
  for (int mt = 0; mt < 4; ++mt)
#pragma unroll
    for (int j = 0; j < 4; ++j) {
      int r = mt * 16 + kg * 4 + j;
      float mean = stM[r], rs = stR[r];
#pragma unroll
      for (int nt = 0; nt < 4; ++nt) {
        int n = (w * 4 + nt) * 16 + ln15;
        float v = (acc[mt][nt][j] - mean) * rs * gv[nt] + bv[nt];
        *(_Float16*)(dst + ((r * 1024 + n * 2) ^ ((r & 7) << 4))) = (_Float16)v;
      }
    }
  __syncthreads();
}

// ---------------- fused FC: seg+dist -> LN -> fc1 -> LN -> fc2 -> LN -> fc3 ----------------
__global__ __launch_bounds__(512, 4) void k_fc(
    const unsigned* __restrict__ segin, const int* __restrict__ dist,
    const float* __restrict__ dist_tab,
    const float* __restrict__ g1, const float* __restrict__ be1,
    const _Float16* __restrict__ wf1t, const float* __restrict__ bf1,
    const float* __restrict__ g2, const float* __restrict__ be2,
    const _Float16* __restrict__ wf2t, const float* __restrict__ bf2,
    const float* __restrict__ g3, const float* __restrict__ be3,
    const _Float16* __restrict__ wf3t, const float* __restrict__ bf3,
    float* __restrict__ x3) {
  __shared__ __align__(16) char bufA[65536];  // [64][512] f16, rowB 1024
  __shared__ float st1[512], st2[512];
  __shared__ float stM[64], stR[64];

  const int tid = threadIdx.x;
  const int r0 = blockIdx.x * 64;

  // ---- prologue: seg + dist emb -> relu -> LN1 -> bufA (f16, swizzled) ----
  {
    const int r = tid >> 3, cp = tid & 7;
    const int gr = r0 + r;
    int di = dist[gr];
    const float* dt = dist_tab + (size_t)di * 512;
    float s1 = 0.f, s2 = 0.f;
#pragma unroll
    for (int i = 0; i < 16; ++i) {
      int c = cp * 64 + i * 4;
      uint4 sv = *(const uint4*)(segin + (size_t)gr * 512 + c);
      float v0 = (sv.x == NEG_FLIP) ? 0.f : unflipf(sv.x);
      float v1 = (sv.y == NEG_FLIP) ? 0.f : unflipf(sv.y);
      float v2 = (sv.z == NEG_FLIP) ? 0.f : unflipf(sv.z);
      float v3 = (sv.w == NEG_FLIP) ? 0.f : unflipf(sv.w);
      if (di) { v0 += dt[c]; v1 += dt[c + 1]; v2 += dt[c + 2]; v3 += dt[c + 3]; }
      v0 = fmaxf(v0, 0.f); v1 = fmaxf(v1, 0.f); v2 = fmaxf(v2, 0.f); v3 = fmaxf(v3, 0.f);
      s1 += v0 + v1 + v2 + v3;
      s2 += v0 * v0 + v1 * v1 + v2 * v2 + v3 * v3;
      half4 hv = {(_Float16)v0, (_Float16)v1, (_Float16)v2, (_Float16)v3};
      *(half4*)(bufA + ((r * 1024 + c * 2) ^ ((r & 7) << 4))) = hv;
    }
#pragma unroll
    for (int o = 4; o > 0; o >>= 1) { s1 += __shfl_down(s1, o); s2 += __shfl_down(s2, o); }
    if (cp == 0) {
      float mean = s1 * (1.f / 512.f);
      float var = s2 * (1.f / 512.f) - mean * mean;
      stM[r] = mean;
      stR[r] = rsqrtf(var + 1e-5f);
    }
    __syncthreads();
    float mean = stM[r], rs = stR[r];
#pragma unroll
    for (int i = 0; i < 16; ++i) {
      int c = cp * 64 + i * 4;
      int byte = (r * 1024 + c * 2) ^ ((r & 7) << 4);
      half4 hv = *(half4*)(bufA + byte);
      float4 g4 = *(const float4*)(g1 + c);
      float4 b4 = *(const float4*)(be1 + c);
      half4 ov = {(_Float16)(((float)hv[0] - mean) * rs * g4.x + b4.x),
                  (_Float16)(((float)hv[1] - mean) * rs * g4.y + b4.y),
                  (_Float16)(((float)hv[2] - mean) * rs * g4.z + b4.z),
                  (_Float16)(((float)hv[3] - mean) * rs * g4.w + b4.w)};
      *(half4*)(bufA + byte) = ov;
    }
  }
  __syncthreads();

  {  // fc1: bufA @ wf1 -> LN2 -> bufA (in-place)
    f32x4 acc[4][4];
    init_acc<4>(bf1, acc, tid);
    do_layer_g<512, 4>(wf1t, bufA, acc, tid);
    epi_ln_store(acc, bufA, st1, st2, stM, stR, g2, be2, tid);
  }
  {  // fc2: bufA @ wf2 -> LN3 -> bufA (in-place)
    f32x4 acc[4][4];
    init_acc<4>(bf2, acc, tid);
    do_layer_g<512, 4>(wf2t, bufA, acc, tid);
    epi_ln_store(acc, bufA, st1, st2, stM, stR, g3, be3, tid);
  }
  {  // fc3: bufA @ wf3 [64x512]@[512x16], 4-wave M-split, direct store
    const int w = tid >> 6, lane = tid & 63, ln15 = lane & 15, kg = lane >> 4;
    if (w < 4) {
      f32x4 acc3 = {0.f, 0.f, 0.f, 0.f};
#pragma unroll
      for (int c = 0; c < 16; ++c) {
        half8 b = *(const half8*)((const char*)wf3t + ln15 * 1024 + c * 64 + kg * 16);
        int row = w * 16 + ln15;
        half8 a = *(const half8*)(bufA + ((row * 1024 + c * 64 + kg * 16) ^ ((row & 7) << 4)));
        acc3 = __builtin_amdgcn_mfma_f32_16x16x32_f16(a, b, acc3, 0, 0, 0);
      }
#pragma unroll
      for (int j = 0; j < 4; ++j)
        x3[(size_t)(r0 + w * 16 + kg * 4 + j) * 16 + ln15] = acc3[j] + bf3[ln15];
    }
  }
}

// ---------------- triu mask + symmetrize ----------------
__global__ void k_sym(const float* __restrict__ x3, float* __restrict__ out) {
  int t = blockIdx.x * 256 + threadIdx.x;
  if (t >= SEGN * 4) return;
  int q = t & 3;
  int cell = t >> 2;
  int j = cell % Nn;
  int tmp = cell / Nn;
  int i = tmp % Nn;
  int b = tmp / Nn;
  float4 v = make_float4(0.f, 0.f, 0.f, 0.f);
  if (i <= j) v = *(const float4*)&x3[(size_t)cell * 16 + q * 4];
  if (j <= i) {
    int cell2 = (b * Nn + j) * Nn + i;
    float4 u = *(const float4*)&x3[(size_t)cell2 * 16 + q * 4];
    v.x += u.x; v.y += u.y; v.z += u.z; v.w += u.w;
  }
  *(float4*)&out[(size_t)t * 4] = v;
}

extern "C" void kernel_launch(void* const* d_in, const int* in_sizes, int n_in,
                              void* d_out, int out_size, void* d_ws, size_t ws_size,
                              hipStream_t stream) {
  const int*   rel_type  = (const int*)d_in[0];
  const float* rel_error = (const float*)d_in[1];
  const int*   edge_pos  = (const int*)d_in[2];
  const int*   dist      = (const int*)d_in[3];
  const int*   rel_row   = (const int*)d_in[4];
  const float* type_tab = (const float*)d_in[8];
  const float* pos_tab  = (const float*)d_in[9];
  const float* dist_tab = (const float*)d_in[10];
  const float* w1 = (const float*)d_in[11]; const float* b1 = (const float*)d_in[12];
  const float* w2 = (const float*)d_in[13]; const float* b2 = (const float*)d_in[14];
  const float* w3 = (const float*)d_in[15]; const float* b3 = (const float*)d_in[16];
  const float* g1 = (const float*)d_in[17]; const float* be1 = (const float*)d_in[18];
  const float* wf1 = (const float*)d_in[19]; const float* bf1 = (const float*)d_in[20];
  const float* g2 = (const float*)d_in[21]; const float* be2 = (const float*)d_in[22];
  const float* wf2 = (const float*)d_in[23]; const float* bf2 = (const float*)d_in[24];
  const float* g3 = (const float*)d_in[25]; const float* be3 = (const float*)d_in[26];
  const float* wf3 = (const float*)d_in[27]; const float* bf3 = (const float*)d_in[28];

  const int E = in_sizes[0];
  const size_t seg_bytes = (size_t)SEGN * 512 * 4;     // 209.7 MB
  const size_t x3_bytes  = (size_t)SEGN * 16 * 4;      // 6.55 MB
  const size_t wt_elems  = 32768 + 131072 + 262144 * 3 + 8192;
  if (ws_size < seg_bytes + x3_bytes + wt_elems * 2) return;

  unsigned*  seg = (unsigned*)d_ws;
  float*     x3  = (float*)((char*)d_ws + seg_bytes);
  _Float16*  w1t = (_Float16*)((char*)d_ws + seg_bytes + x3_bytes);
  _Float16*  w2t = w1t + 32768;
  _Float16*  w3t = w2t + 131072;
  _Float16*  wf1t = w3t + 262144;
  _Float16*  wf2t = wf1t + 262144;
  _Float16*  wf3t = wf2t + 262144;
  float*     out = (float*)d_out;

  k_prep<<<3744, 256, 0, stream>>>(w1, w2, w3, wf1, wf2, wf3,
                                   w1t, w2t, w3t, wf1t, wf2t, wf3t);
  k_init<<<2048, 256, 0, stream>>>((uint4*)seg, SEGN * 512 / 4);
  k_edge<<<(E + 63) / 64, 512, 0, stream>>>(rel_type, rel_error, edge_pos, rel_row,
                                            type_tab, pos_tab, w1t, b1, w2t, b2, w3t, b3,
                                            seg, E);
  k_fc<<<SEGN / 64, 512, 0, stream>>>(seg, dist, dist_tab,
                                      g1, be1, wf1t, bf1,
                                      g2, be2, wf2t, bf2,
                                      g3, be3, wf3t, bf3, x3);
  k_sym<<<(SEGN * 4 + 255) / 256, 256, 0, stream>>>(x3, out);
}

// Round 5
// 727.421 us; speedup vs baseline: 7.8929x; 1.2361x over previous
//
#include <hip/hip_runtime.h>

typedef __attribute__((ext_vector_type(8))) _Float16 half8;
typedef __attribute__((ext_vector_type(4))) _Float16 half4;
typedef __attribute__((ext_vector_type(4))) float f32x4;

constexpr int Bn = 4;
constexpr int Nn = 160;
constexpr int SEGN = Bn * Nn * Nn;        // 102400 segments
constexpr unsigned NEG_FLIP = 0x007FFFFFu; // flip(-inf)

__device__ __forceinline__ unsigned flipf(float f) {
  unsigned u = __float_as_uint(f);
  return (u & 0x80000000u) ? ~u : (u | 0x80000000u);
}
__device__ __forceinline__ float unflipf(unsigned s) {
  return __uint_as_float((s & 0x80000000u) ? (s ^ 0x80000000u) : ~s);
}

// ---------------- init segment buffer to flip(-inf) ----------------
__global__ void k_init(uint4* __restrict__ seg, int n4) {
  int i = blockIdx.x * blockDim.x + threadIdx.x;
  int stride = gridDim.x * blockDim.x;
  uint4 v = make_uint4(NEG_FLIP, NEG_FLIP, NEG_FLIP, NEG_FLIP);
  for (; i < n4; i += stride) seg[i] = v;
}

// ------- weight prepass: f32 [K][N] -> f16 chunk-blocked [k/32][N][32] -------
// (wf3: [512][16] -> [16][512] plain transpose)
__global__ void k_prep(const float* __restrict__ w1, const float* __restrict__ w2,
                       const float* __restrict__ w3, const float* __restrict__ wf1,
                       const float* __restrict__ wf2, const float* __restrict__ wf3,
                       _Float16* __restrict__ o1, _Float16* __restrict__ o2,
                       _Float16* __restrict__ o3, _Float16* __restrict__ of1,
                       _Float16* __restrict__ of2, _Float16* __restrict__ of3) {
  int t = blockIdx.x * 256 + threadIdx.x;
  const float* src; _Float16* dst; int N, local; bool is3 = false;
  if (t < 32768)       { src = w1;  dst = o1;  N = 256; local = t; }
  else if (t < 163840) { src = w2;  dst = o2;  N = 512; local = t - 32768; }
  else if (t < 425984) { src = w3;  dst = o3;  N = 512; local = t - 163840; }
  else if (t < 688128) { src = wf1; dst = of1; N = 512; local = t - 425984; }
  else if (t < 950272) { src = wf2; dst = of2; N = 512; local = t - 688128; }
  else if (t < 958464) { src = wf3; dst = of3; N = 16;  local = t - 950272; is3 = true; }
  else return;
  int k = local / N;
  int n = local - k * N;
  if (is3) dst[n * 512 + k] = (_Float16)src[local];
  else dst[(size_t)((k >> 5) * N + n) * 32 + (k & 31)] = (_Float16)src[local];
}

// ---------------- barrier-free MFMA layer, B direct from global (L2) ----------------
// A in LDS: f16 [rows][K], rowB = 2K bytes, byte ^= ((row&7)<<4).
// W chunk-blocked global [c][N][32] f16: a wave's (n-tile, kg) half8 is a
// coalesced 16B slice of a contiguous 1KB region.
template <int K, int NT>
__device__ __forceinline__ void do_layer_g(const _Float16* __restrict__ wt,
                                           const char* a_base,
                                           f32x4 (&acc)[4][NT], int tid) {
  constexpr int C = K / 32;
  constexpr int N = NT * 128;
  constexpr int rowB = K * 2;
  const int w = tid >> 6, lane = tid & 63, ln15 = lane & 15, kg = lane >> 4;
  const char* wb = (const char*)wt;
#pragma unroll
  for (int c = 0; c < C; ++c) {
    half8 a[4], b[NT];
#pragma unroll
    for (int nt = 0; nt < NT; ++nt) {
      int n = (w * NT + nt) * 16 + ln15;
      b[nt] = *(const half8*)(wb + (size_t)c * (N * 64) + n * 64 + kg * 16);
    }
#pragma unroll
    for (int mt = 0; mt < 4; ++mt) {
      int row = mt * 16 + ln15;
      int byte = (row * rowB + c * 64 + kg * 16) ^ ((row & 7) << 4);
      a[mt] = *(const half8*)(a_base + byte);
    }
#pragma unroll
    for (int mt = 0; mt < 4; ++mt)
#pragma unroll
      for (int nt = 0; nt < NT; ++nt)
        acc[mt][nt] = __builtin_amdgcn_mfma_f32_16x16x32_f16(a[mt], b[nt], acc[mt][nt], 0, 0, 0);
  }
}

template <int NT>
__device__ __forceinline__ void init_acc(const float* __restrict__ bias,
                                         f32x4 (&acc)[4][NT], int tid) {
  const int w = tid >> 6, ln15 = tid & 15;
#pragma unroll
  for (int nt = 0; nt < NT; ++nt) {
    float bv = bias[(w * NT + nt) * 16 + ln15];
    f32x4 s = {bv, bv, bv, bv};
#pragma unroll
    for (int mt = 0; mt < 4; ++mt) acc[mt][nt] = s;
  }
}

// C layout: col = lane&15, row = (lane>>4)*4 + j  [m89 verified]
template <int NT, bool RELU>
__device__ __forceinline__ void store_h(char* h, int rowB, const f32x4 (&acc)[4][NT], int tid) {
  const int w = tid >> 6, lane = tid & 63, ln15 = lane & 15, kg = lane >> 4;
#pragma unroll
  for (int mt = 0; mt < 4; ++mt)
#pragma unroll
    for (int nt = 0; nt < NT; ++nt)
#pragma unroll
      for (int j = 0; j < 4; ++j) {
        int row = mt * 16 + kg * 4 + j;
        int n = (w * NT + nt) * 16 + ln15;
        float v = acc[mt][nt][j];
        if (RELU) v = fmaxf(v, 0.f);
        *(_Float16*)(h + ((row * rowB + n * 2) ^ ((row & 7) << 4))) = (_Float16)v;
      }
}

// ---------------- fused edge MLP (MFMA) + scatter-max ----------------
__global__ __launch_bounds__(512) void k_edge(
    const int* __restrict__ rel_type, const float* __restrict__ rel_error,
    const int* __restrict__ edge_pos, const int* __restrict__ rel_row,
    const float* __restrict__ type_tab, const float* __restrict__ pos_tab,
    const _Float16* __restrict__ w1t, const float* __restrict__ b1,
    const _Float16* __restrict__ w2t, const float* __restrict__ b2,
    const _Float16* __restrict__ w3t, const float* __restrict__ b3,
    unsigned* __restrict__ seg, int E) {
  __shared__ __align__(16) char smem[98304];
  __shared__ int rr[64];
  char* h1 = smem;            // [64][256] f16, rowB 512
  char* h2 = smem + 32768;    // [64][512] f16, rowB 1024
  char* e  = smem + 32768;    // [64][128] f16, rowB 256 (dead before h2 written)

  const int tid = threadIdx.x;
  const int e0 = blockIdx.x * 64;

  // ---- build e tile ----
  {
    int r = tid >> 3, c0 = (tid & 7) * 16;
    int re = min(e0 + r, E - 1);
    int rt = rel_type[re];
    int ep = edge_pos[re];
#pragma unroll
    for (int s = 0; s < 2; ++s) {
      half8 hv;
#pragma unroll
      for (int q = 0; q < 8; ++q) {
        int cc = c0 + s * 8 + q;
        float v = (cc < 120) ? (rt ? type_tab[rt * 120 + cc] : 0.f)
                             : rel_error[(size_t)re * 8 + (cc - 120)];
        v += pos_tab[ep * 128 + cc];
        hv[q] = (_Float16)v;
      }
      int byte = (r * 256 + (c0 + s * 8) * 2) ^ ((r & 7) << 4);
      *(half8*)(e + byte) = hv;
    }
    if (tid < 64) rr[tid] = rel_row[min(e0 + tid, E - 1)];
  }
  __syncthreads();

  {  // layer 1: [64x128]@[128x256] + relu -> h1
    f32x4 acc[4][2];
    init_acc<2>(b1, acc, tid);
    do_layer_g<128, 2>(w1t, e, acc, tid);
    store_h<2, true>(h1, 512, acc, tid);
  }
  __syncthreads();
  {  // layer 2: [64x256]@[256x512] + relu -> h2 (overwrites e, safe: e reads drained)
    f32x4 acc[4][4];
    init_acc<4>(b2, acc, tid);
    do_layer_g<256, 4>(w2t, h1, acc, tid);
    store_h<4, true>(h2, 1024, acc, tid);
  }
  __syncthreads();
  {  // layer 3: [64x512]@[512x512] -> scatter-max
    f32x4 acc[4][4];
    init_acc<4>(b3, acc, tid);
    do_layer_g<512, 4>(w3t, h2, acc, tid);

    const int w = tid >> 6, lane = tid & 63, ln15 = lane & 15, kg = lane >> 4;
#pragma unroll
    for (int mt = 0; mt < 4; ++mt) {
      int rbase = mt * 16 + kg * 4;
      float m[4];
      int cur = rr[rbase];
#pragma unroll
      for (int nt = 0; nt < 4; ++nt) m[nt] = acc[mt][nt][0];
#pragma unroll
      for (int j = 1; j < 4; ++j) {
        int rj = rr[rbase + j];
        if (rj == cur) {
#pragma unroll
          for (int nt = 0; nt < 4; ++nt) m[nt] = fmaxf(m[nt], acc[mt][nt][j]);
        } else {
          unsigned* dst = seg + (size_t)cur * 512;
#pragma unroll
          for (int nt = 0; nt < 4; ++nt)
            atomicMax(dst + (w * 4 + nt) * 16 + ln15, flipf(m[nt]));
          cur = rj;
#pragma unroll
          for (int nt = 0; nt < 4; ++nt) m[nt] = acc[mt][nt][j];
        }
      }
      unsigned* dst = seg + (size_t)cur * 512;
#pragma unroll
      for (int nt = 0; nt < 4; ++nt)
        atomicMax(dst + (w * 4 + nt) * 16 + ln15, flipf(m[nt]));
    }
  }
}

// ---- in-register epilogue: relu -> LN (shfl + 2-stage LDS) -> store f16 ----
__device__ __forceinline__ void epi_ln_store(f32x4 (&acc)[4][4], char* dst,
                                             float* st1, float* st2,
                                             float* stM, float* stR,
                                             const float* __restrict__ g,
                                             const float* __restrict__ be, int tid) {
  const int w = tid >> 6, lane = tid & 63, ln15 = lane & 15, kg = lane >> 4;
#pragma unroll
  for (int mt = 0; mt < 4; ++mt)
#pragma unroll
    for (int nt = 0; nt < 4; ++nt)
#pragma unroll
      for (int j = 0; j < 4; ++j) acc[mt][nt][j] = fmaxf(acc[mt][nt][j], 0.f);
#pragma unroll
  for (int mt = 0; mt < 4; ++mt)
#pragma unroll
    for (int j = 0; j < 4; ++j) {
      float a = 0.f, b = 0.f;
#pragma unroll
      for (int nt = 0; nt < 4; ++nt) { float v = acc[mt][nt][j]; a += v; b += v * v; }
#pragma unroll
      for (int m = 1; m < 16; m <<= 1) { a += __shfl_xor(a, m); b += __shfl_xor(b, m); }
      if (ln15 == 0) {
        int r = mt * 16 + kg * 4 + j;
        st1[w * 64 + r] = a;
        st2[w * 64 + r] = b;
      }
    }
  __syncthreads();
  if (tid < 64) {
    float a = 0.f, b = 0.f;
#pragma unroll
    for (int ww = 0; ww < 8; ++ww) { a += st1[ww * 64 + tid]; b += st2[ww * 64 + tid]; }
    float mean = a * (1.f / 512.f);
    float var = b * (1.f / 512.f) - mean * mean;
    stM[tid] = mean;
    stR[tid] = rsqrtf(var + 1e-5f);
  }
  __syncthreads();
  float gv[4], bv[4];
#pragma unroll
  for (int nt = 0; nt < 4; ++nt) {
    int n = (w * 4 + nt) * 16 + ln15;
    gv[nt] = g[n]; bv[nt] = be[n];
  }
#pragma unroll
  for (int mt = 0; mt < 4; ++mt)
#pragma unroll
    for (int j = 0; j < 4; ++j) {
      int r = mt * 16 + kg * 4 + j;
      float mean = stM[r], rs = stR[r];
#pragma unroll
      for (int nt = 0; nt < 4; ++nt) {
        int n = (w * 4 + nt) * 16 + ln15;
        float v = (acc[mt][nt][j] - mean) * rs * gv[nt] + bv[nt];
        *(_Float16*)(dst + ((r * 1024 + n * 2) ^ ((r & 7) << 4))) = (_Float16)v;
      }
    }
  __syncthreads();
}

// ---------------- fused FC: seg+dist -> LN -> fc1 -> LN -> fc2 -> LN -> fc3 ----------------
// launch_bounds(512, 2): 2 blocks/CU (CUDA-style 2nd arg) -> 128-VGPR budget.
// (512,4) clamped to 64 VGPRs and spilled the whole accumulator -> 400MB scratch.
__global__ __launch_bounds__(512, 2) void k_fc(
    const unsigned* __restrict__ segin, const int* __restrict__ dist,
    const float* __restrict__ dist_tab,
    const float* __restrict__ g1, const float* __restrict__ be1,
    const _Float16* __restrict__ wf1t, const float* __restrict__ bf1,
    const float* __restrict__ g2, const float* __restrict__ be2,
    const _Float16* __restrict__ wf2t, const float* __restrict__ bf2,
    const float* __restrict__ g3, const float* __restrict__ be3,
    const _Float16* __restrict__ wf3t, const float* __restrict__ bf3,
    float* __restrict__ x3) {
  __shared__ __align__(16) char bufA[65536];  // [64][512] f16, rowB 1024
  __shared__ float st1[512], st2[512];
  __shared__ float stM[64], stR[64];

  const int tid = threadIdx.x;
  const int r0 = blockIdx.x * 64;

  // ---- prologue: seg + dist emb -> relu -> LN1 -> bufA (f16, swizzled) ----
  {
    const int r = tid >> 3, cp = tid & 7;
    const int gr = r0 + r;
    int di = dist[gr];
    const float* dt = dist_tab + (size_t)di * 512;
    float s1 = 0.f, s2 = 0.f;
#pragma unroll
    for (int i = 0; i < 16; ++i) {
      int c = cp * 64 + i * 4;
      uint4 sv = *(const uint4*)(segin + (size_t)gr * 512 + c);
      float v0 = (sv.x == NEG_FLIP) ? 0.f : unflipf(sv.x);
      float v1 = (sv.y == NEG_FLIP) ? 0.f : unflipf(sv.y);
      float v2 = (sv.z == NEG_FLIP) ? 0.f : unflipf(sv.z);
      float v3 = (sv.w == NEG_FLIP) ? 0.f : unflipf(sv.w);
      if (di) { v0 += dt[c]; v1 += dt[c + 1]; v2 += dt[c + 2]; v3 += dt[c + 3]; }
      v0 = fmaxf(v0, 0.f); v1 = fmaxf(v1, 0.f); v2 = fmaxf(v2, 0.f); v3 = fmaxf(v3, 0.f);
      s1 += v0 + v1 + v2 + v3;
      s2 += v0 * v0 + v1 * v1 + v2 * v2 + v3 * v3;
      half4 hv = {(_Float16)v0, (_Float16)v1, (_Float16)v2, (_Float16)v3};
      *(half4*)(bufA + ((r * 1024 + c * 2) ^ ((r & 7) << 4))) = hv;
    }
#pragma unroll
    for (int o = 4; o > 0; o >>= 1) { s1 += __shfl_down(s1, o); s2 += __shfl_down(s2, o); }
    if (cp == 0) {
      float mean = s1 * (1.f / 512.f);
      float var = s2 * (1.f / 512.f) - mean * mean;
      stM[r] = mean;
      stR[r] = rsqrtf(var + 1e-5f);
    }
    __syncthreads();
    float mean = stM[r], rs = stR[r];
#pragma unroll
    for (int i = 0; i < 16; ++i) {
      int c = cp * 64 + i * 4;
      int byte = (r * 1024 + c * 2) ^ ((r & 7) << 4);
      half4 hv = *(half4*)(bufA + byte);
      float4 g4 = *(const float4*)(g1 + c);
      float4 b4 = *(const float4*)(be1 + c);
      half4 ov = {(_Float16)(((float)hv[0] - mean) * rs * g4.x + b4.x),
                  (_Float16)(((float)hv[1] - mean) * rs * g4.y + b4.y),
                  (_Float16)(((float)hv[2] - mean) * rs * g4.z + b4.z),
                  (_Float16)(((float)hv[3] - mean) * rs * g4.w + b4.w)};
      *(half4*)(bufA + byte) = ov;
    }
  }
  __syncthreads();

  {  // fc1: bufA @ wf1 -> LN2 -> bufA (in-place)
    f32x4 acc[4][4];
    init_acc<4>(bf1, acc, tid);
    do_layer_g<512, 4>(wf1t, bufA, acc, tid);
    epi_ln_store(acc, bufA, st1, st2, stM, stR, g2, be2, tid);
  }
  {  // fc2: bufA @ wf2 -> LN3 -> bufA (in-place)
    f32x4 acc[4][4];
    init_acc<4>(bf2, acc, tid);
    do_layer_g<512, 4>(wf2t, bufA, acc, tid);
    epi_ln_store(acc, bufA, st1, st2, stM, stR, g3, be3, tid);
  }
  {  // fc3: bufA @ wf3 [64x512]@[512x16], 4-wave M-split, direct store
    const int w = tid >> 6, lane = tid & 63, ln15 = lane & 15, kg = lane >> 4;
    if (w < 4) {
      f32x4 acc3 = {0.f, 0.f, 0.f, 0.f};
#pragma unroll
      for (int c = 0; c < 16; ++c) {
        half8 b = *(const half8*)((const char*)wf3t + ln15 * 1024 + c * 64 + kg * 16);
        int row = w * 16 + ln15;
        half8 a = *(const half8*)(bufA + ((row * 1024 + c * 64 + kg * 16) ^ ((row & 7) << 4)));
        acc3 = __builtin_amdgcn_mfma_f32_16x16x32_f16(a, b, acc3, 0, 0, 0);
      }
#pragma unroll
      for (int j = 0; j < 4; ++j)
        x3[(size_t)(r0 + w * 16 + kg * 4 + j) * 16 + ln15] = acc3[j] + bf3[ln15];
    }
  }
}

// ---------------- triu mask + symmetrize ----------------
__global__ void k_sym(const float* __restrict__ x3, float* __restrict__ out) {
  int t = blockIdx.x * 256 + threadIdx.x;
  if (t >= SEGN * 4) return;
  int q = t & 3;
  int cell = t >> 2;
  int j = cell % Nn;
  int tmp = cell / Nn;
  int i = tmp % Nn;
  int b = tmp / Nn;
  float4 v = make_float4(0.f, 0.f, 0.f, 0.f);
  if (i <= j) v = *(const float4*)&x3[(size_t)cell * 16 + q * 4];
  if (j <= i) {
    int cell2 = (b * Nn + j) * Nn + i;
    float4 u = *(const float4*)&x3[(size_t)cell2 * 16 + q * 4];
    v.x += u.x; v.y += u.y; v.z += u.z; v.w += u.w;
  }
  *(float4*)&out[(size_t)t * 4] = v;
}

extern "C" void kernel_launch(void* const* d_in, const int* in_sizes, int n_in,
                              void* d_out, int out_size, void* d_ws, size_t ws_size,
                              hipStream_t stream) {
  const int*   rel_type  = (const int*)d_in[0];
  const float* rel_error = (const float*)d_in[1];
  const int*   edge_pos  = (const int*)d_in[2];
  const int*   dist      = (const int*)d_in[3];
  const int*   rel_row   = (const int*)d_in[4];
  const float* type_tab = (const float*)d_in[8];
  const float* pos_tab  = (const float*)d_in[9];
  const float* dist_tab = (const float*)d_in[10];
  const float* w1 = (const float*)d_in[11]; const float* b1 = (const float*)d_in[12];
  const float* w2 = (const float*)d_in[13]; const float* b2 = (const float*)d_in[14];
  const float* w3 = (const float*)d_in[15]; const float* b3 = (const float*)d_in[16];
  const float* g1 = (const float*)d_in[17]; const float* be1 = (const float*)d_in[18];
  const float* wf1 = (const float*)d_in[19]; const float* bf1 = (const float*)d_in[20];
  const float* g2 = (const float*)d_in[21]; const float* be2 = (const float*)d_in[22];
  const float* wf2 = (const float*)d_in[23]; const float* bf2 = (const float*)d_in[24];
  const float* g3 = (const float*)d_in[25]; const float* be3 = (const float*)d_in[26];
  const float* wf3 = (const float*)d_in[27]; const float* bf3 = (const float*)d_in[28];

  const int E = in_sizes[0];
  const size_t seg_bytes = (size_t)SEGN * 512 * 4;     // 209.7 MB
  const size_t x3_bytes  = (size_t)SEGN * 16 * 4;      // 6.55 MB
  const size_t wt_elems  = 32768 + 131072 + 262144 * 3 + 8192;
  if (ws_size < seg_bytes + x3_bytes + wt_elems * 2) return;

  unsigned*  seg = (unsigned*)d_ws;
  float*     x3  = (float*)((char*)d_ws + seg_bytes);
  _Float16*  w1t = (_Float16*)((char*)d_ws + seg_bytes + x3_bytes);
  _Float16*  w2t = w1t + 32768;
  _Float16*  w3t = w2t + 131072;
  _Float16*  wf1t = w3t + 262144;
  _Float16*  wf2t = wf1t + 262144;
  _Float16*  wf3t = wf2t + 262144;
  float*     out = (float*)d_out;

  k_prep<<<3744, 256, 0, stream>>>(w1, w2, w3, wf1, wf2, wf3,
                                   w1t, w2t, w3t, wf1t, wf2t, wf3t);
  k_init<<<2048, 256, 0, stream>>>((uint4*)seg, SEGN * 512 / 4);
  k_edge<<<(E + 63) / 64, 512, 0, stream>>>(rel_type, rel_error, edge_pos, rel_row,
                                            type_tab, pos_tab, w1t, b1, w2t, b2, w3t, b3,
                                            seg, E);
  k_fc<<<SEGN / 64, 512, 0, stream>>>(seg, dist, dist_tab,
                                      g1, be1, wf1t, bf1,
                                      g2, be2, wf2t, bf2,
                                      g3, be3, wf3t, bf3, x3);
  k_sym<<<(SEGN * 4 + 255) / 256, 256, 0, stream>>>(x3, out);
}